// Round 4
// baseline (4473.667 us; speedup 1.0000x reference)
//
#include <hip/hip_runtime.h>
#include <cmath>

#define DI __device__ __forceinline__

constexpr int B_=2, S_=2048, E_=1024, H_=1344, NH_=4, DH_=336;
constexpr int BS_=B_*S_, H2_=2*H_;
constexpr int NG_=B_*NH_*S_;   // 16384

constexpr size_t N_X=(size_t)BS_*E_;
constexpr size_t N_WUP=(size_t)E_*H2_;
constexpr size_t N_WDN=(size_t)H_*E_;
constexpr size_t N_BSH=(size_t)BS_*H_;
constexpr size_t N_BSH2=(size_t)BS_*H2_;
constexpr size_t N_WH=5376, N_WG=16128, N_CK=4*H_;

// ---- ws layout (floats); every size is a multiple of 16 -> all 64B aligned
constexpr size_t O_IGB = 64;
constexpr size_t O_LOGF= O_IGB + NG_;
constexpr size_t O_AB  = O_LOGF+ NG_;
constexpr size_t O_MB  = O_AB  + NG_;
constexpr size_t O_MTB = O_MB  + NG_;
constexpr size_t O_CK  = O_MTB + NG_;
constexpr size_t O_CB  = O_CK  + N_CK;
constexpr size_t O_WQ  = O_CB  + H_;
constexpr size_t O_WK  = O_WQ  + N_WH;
constexpr size_t O_WV  = O_WK  + N_WH;
constexpr size_t O_WIG = O_WV  + N_WH;
constexpr size_t O_BIG = O_WIG + N_WG;
constexpr size_t O_WFG = O_BIG + 16;
constexpr size_t O_BFG = O_WFG + N_WG;
constexpr size_t O_LNW = O_BFG + 16;
constexpr size_t O_SKP = O_LNW + H_;
constexpr size_t O_FX  = O_SKP + H_;
constexpr size_t O_FWUP= O_FX  + N_X;
constexpr size_t O_FWDN= O_FWUP+ N_WUP;
constexpr size_t O_XIN = O_FWDN+ N_WDN;
constexpr size_t O_ACT = O_XIN + N_BSH2;
constexpr size_t O_QB  = O_ACT + N_BSH;
constexpr size_t O_KB  = O_QB  + N_BSH;
constexpr size_t O_VB  = O_KB  + N_BSH;
constexpr size_t O_HRAW= O_VB  + N_BSH;

DI float bf2f(unsigned int u){union{unsigned int i;float f;}v;v.i=(u&0xffffu)<<16;return v.f;}
DI unsigned short f2bf(float f){union{float f;unsigned int i;}v;v.f=f;unsigned int x=v.i;
  return (unsigned short)((x+0x7fffu+((x>>16)&1u))>>16);}
DI float siluf(float x){return x/(1.f+expf(-x));}
DI float logsigf(float x){return (x>=0.f)?-log1pf(expf(-x)):x-log1pf(expf(x));}

// ---- dtype detect: fp32 read as u16 -> ~44% of low halves have huge exponents
__global__ __launch_bounds__(256) void detect_k(const unsigned short* __restrict__ xraw,
                                                int* __restrict__ flag){
  __shared__ int cnt_s;
  if(threadIdx.x==0) cnt_s=0;
  __syncthreads();
  int c=0;
  for(int i=threadIdx.x;i<2048;i+=256){
    const unsigned e=(xraw[i]>>7)&0xFFu;
    if(e>=0x90u) c++;
  }
  atomicAdd(&cnt_s,c);
  __syncthreads();
  if(threadIdx.x==0) *flag=(cnt_s>16)?0:1;
}

__global__ __launch_bounds__(256) void convert_k(const void* __restrict__ src,
                                                 float* __restrict__ dst,int n,
                                                 const int* __restrict__ flag){
  const int i=blockIdx.x*256+threadIdx.x;
  if(i>=n) return;
  if(*flag) dst[i]=bf2f(((const unsigned short*)src)[i]);
  else      dst[i]=((const float*)src)[i];
}

__global__ __launch_bounds__(256) void out_cast_k(const float* __restrict__ src,void* dst,
                                                  const int* __restrict__ flag){
  const int i=blockIdx.x*256+threadIdx.x;
  if(i>=(int)N_X) return;
  const float v=src[i];
  if(*flag) ((unsigned short*)dst)[i]=f2bf(v);
  else      ((float*)dst)[i]=v;
}

// ---- textbook 16x16 tiled GEMM (fp32): C[M,N] = A[M,K] @ B[K,N]
__global__ __launch_bounds__(256) void gemm_s(const float* __restrict__ A,
                                              const float* __restrict__ Bm,
                                              float* __restrict__ C,
                                              int M,int N,int K,int lda,int ldb,int ldc){
  __shared__ float As[16][17], Bs[16][17];
  const int tx=threadIdx.x&15, ty=threadIdx.x>>4;
  const int row=blockIdx.y*16+ty, col=blockIdx.x*16+tx;
  float acc=0.f;
  for(int k0=0;k0<K;k0+=16){
    As[ty][tx]=A[(size_t)row*lda+k0+tx];
    Bs[ty][tx]=Bm[(size_t)(k0+ty)*ldb+col];
    __syncthreads();
#pragma unroll
    for(int kk=0;kk<16;kk++) acc+=As[ty][kk]*Bs[kk][tx];
    __syncthreads();
  }
  C[(size_t)row*ldc+col]=acc;
}

// ---- causal depthwise conv(K=4)+bias -> SiLU, one thread per (b,s,h)
__global__ __launch_bounds__(256) void conv_act_k(const float* __restrict__ xin,
                                                  const float* __restrict__ ck,
                                                  const float* __restrict__ cb,
                                                  float* __restrict__ act){
  const int i=blockIdx.x*256+threadIdx.x;
  if(i>=(int)N_BSH) return;
  const int bs=i/H_, h=i-bs*H_;
  const int b=bs/S_, s=bs-b*S_;
  float xc=cb[h];
#pragma unroll
  for(int w=0;w<4;w++){
    const int sr=s-3+w;
    if(sr>=0) xc+=xin[(size_t)(b*S_+sr)*H2_+h]*ck[w*H_+h];
  }
  act[(size_t)bs*H_+h]=siluf(xc);
}

// ---- headwise q/k/v (PD=4 block-diagonal), one thread per (b,s,h)
__global__ __launch_bounds__(256) void qkv_k(const float* __restrict__ act,
                                             const float* __restrict__ xin,
                                             const float* __restrict__ Wq,
                                             const float* __restrict__ Wk,
                                             const float* __restrict__ Wv,
                                             float* __restrict__ qb,float* __restrict__ kb,
                                             float* __restrict__ vb){
  const int i=blockIdx.x*256+threadIdx.x;
  if(i>=(int)N_BSH) return;
  const int bs=i/H_, h=i-bs*H_;
  const int b=bs/S_, s=bs-b*S_;
  const int ph=h>>2, o=h&3, base=ph*4;
  float q=0.f,k=0.f,v=0.f;
#pragma unroll
  for(int d=0;d<4;d++){
    const float a=act[(size_t)bs*H_+base+d];
    const float x=xin[(size_t)bs*H2_+base+d];
    q+=a*Wq[ph*16+d*4+o];
    k+=a*Wk[ph*16+d*4+o];
    v+=x*Wv[ph*16+d*4+o];
  }
  const int nh=h/DH_, dh=h-nh*DH_;
  const size_t off=((size_t)(b*NH_+nh)*S_+s)*DH_+dh;
  qb[off]=q; kb[off]=k; vb[off]=v;
}

// ---- gate pre-activations, one thread per (b,s,n); serial 3H dot
__global__ __launch_bounds__(256) void gates_k(const float* __restrict__ qb,
                                               const float* __restrict__ kb,
                                               const float* __restrict__ vb,
                                               const float* __restrict__ Wig,
                                               const float* __restrict__ big,
                                               const float* __restrict__ Wfg,
                                               const float* __restrict__ bfg,
                                               float* __restrict__ igb,float* __restrict__ logfb){
  const int i=blockIdx.x*256+threadIdx.x;
  if(i>=BS_*NH_) return;
  const int bs=i>>2, n=i&3;
  const int b=bs/S_, s=bs-b*S_;
  float sig=0.f,sfg=0.f;
  for(int nh=0;nh<NH_;nh++){
    const size_t rb=((size_t)(b*NH_+nh)*S_+s)*DH_;
    for(int dh=0;dh<DH_;dh++){
      const int h=nh*DH_+dh;
      const float q=qb[rb+dh], k=kb[rb+dh], v=vb[rb+dh];
      sig+=q*Wig[h*4+n]+k*Wig[(H_+h)*4+n]+v*Wig[(2*H_+h)*4+n];
      sfg+=q*Wfg[h*4+n]+k*Wfg[(H_+h)*4+n]+v*Wfg[(2*H_+h)*4+n];
    }
  }
  const size_t off=(size_t)(b*NH_+n)*S_+s;
  igb[off]=sig+big[n];
  logfb[off]=logsigf(sfg+bfg[n]);
}

// ---- fully serial per-head scan: c=cumsum(logf), a=ig-c, M=cummax(a), mt=c+M
__global__ __launch_bounds__(64) void scan_k(const float* __restrict__ igb,
                                             const float* __restrict__ logfb,
                                             float* __restrict__ ab,float* __restrict__ Mb,
                                             float* __restrict__ mtb){
  const int head=threadIdx.x;
  if(head>=B_*NH_) return;
  float c=0.f, M=-1e30f;
  const size_t base=(size_t)head*S_;
  for(int s=0;s<S_;s++){
    c+=logfb[base+s];
    const float a=igb[base+s]-c;
    M=fmaxf(M,a);
    ab[base+s]=a; Mb[base+s]=M; mtb[base+s]=c+M;
  }
}

// ---- mLSTM: block = (head, 16 s-rows), thread (r,u) owns one (row, t-residue)
// Sc[s,t] = qk*scale*exp(a[t]-M[s]) for t<=s; h = Sc@V / max(|rowsum|,exp(-mt))
__global__ __launch_bounds__(256) void mlstm_k(const float* __restrict__ qb,
                                               const float* __restrict__ kb,
                                               const float* __restrict__ vb,
                                               const float* __restrict__ ab,
                                               const float* __restrict__ Mb,
                                               const float* __restrict__ mtb,
                                               float* __restrict__ hraw){
  const int head=blockIdx.y, s0=blockIdx.x*16;
  const int r=threadIdx.x>>4, u=threadIdx.x&15;
  __shared__ float Qs[16][344];
  __shared__ float Ks[16][344];   // holds K chunk, then overwritten with V chunk
  __shared__ float Sc[16][16];
  __shared__ float red_n[16][17];
  __shared__ float inv_s[16];
  const size_t hb=(size_t)head*S_;
  for(int idx=threadIdx.x; idx<16*DH_; idx+=256){
    const int rr=idx/DH_, dd=idx-rr*DH_;
    Qs[rr][dd]=qb[(hb+s0+rr)*DH_+dd];
  }
  const float Ml=Mb[hb+s0+r];
  const float scale=0.05455447256f;   // 336^-0.5
  float hacc[21];
#pragma unroll
  for(int m=0;m<21;m++) hacc[m]=0.f;
  float npart=0.f;
  const int nch=(s0>>4)+1;
  for(int c=0;c<nch;c++){
    const int tc=c*16;
    __syncthreads();                        // prev PV reads of Ks/Sc done
    for(int idx=threadIdx.x; idx<16*DH_; idx+=256){
      const int rr=idx/DH_, dd=idx-rr*DH_;
      Ks[rr][dd]=kb[(hb+tc+rr)*DH_+dd];
    }
    __syncthreads();
    float dot=0.f;
    for(int d=0;d<DH_;d++) dot+=Qs[r][d]*Ks[u][d];
    float w=0.f;
    if(tc+u<=s0+r){
      const float e=fminf(ab[hb+tc+u]-Ml,0.f);
      w=dot*scale*expf(e);
    }
    Sc[r][u]=w;
    npart+=w;
    __syncthreads();                        // QK reads of Ks done
    for(int idx=threadIdx.x; idx<16*DH_; idx+=256){
      const int rr=idx/DH_, dd=idx-rr*DH_;
      Ks[rr][dd]=vb[(hb+tc+rr)*DH_+dd];
    }
    __syncthreads();                        // V staged, Sc complete
#pragma unroll
    for(int m=0;m<21;m++){
      const int d=u+16*m;
      float a=hacc[m];
      for(int j=0;j<16;j++) a+=Sc[r][j]*Ks[j][d];
      hacc[m]=a;
    }
  }
  red_n[r][u]=npart;
  __syncthreads();
  if(u==0){
    float ns=0.f;
    for(int j=0;j<16;j++) ns+=red_n[r][j];
    const float mt=mtb[hb+s0+r];
    const float n=fmaxf(fabsf(ns),expf(fminf(fmaxf(-mt,-60.f),60.f)));
    inv_s[r]=1.f/(n+1e-6f);
  }
  __syncthreads();
  const float inv=inv_s[r];
#pragma unroll
  for(int m=0;m<21;m++)
    hraw[(hb+s0+r)*DH_+u+16*m]=hacc[m]*inv;
}

// ---- per-head groupnorm (scale only), one thread per (head,s); hout in (B,S,H)
__global__ __launch_bounds__(256) void gnorm_k(const float* __restrict__ hraw,
                                               const float* __restrict__ lnw,
                                               float* __restrict__ hout){
  const int i=blockIdx.x*256+threadIdx.x;
  if(i>=NG_) return;
  const int head=i>>11, s=i&2047;
  const int b=head>>2, nh=head&3;
  const size_t rb=((size_t)head*S_+s)*DH_;
  float s1=0.f,s2=0.f;
  for(int d=0;d<DH_;d++){const float h=hraw[rb+d]; s1+=h; s2+=h*h;}
  const float mu=s1/336.f;
  const float var=s2/336.f-mu*mu;
  const float rs=rsqrtf(fmaxf(var,0.f)+1e-5f);
  float* orow=hout+((size_t)(b*S_+s))*H_+nh*DH_;
  for(int d=0;d<DH_;d++) orow[d]=(hraw[rb+d]-mu)*rs*lnw[nh*DH_+d];
}

// ---- h_state = (h_out + skip*act) * silu(z)
__global__ __launch_bounds__(256) void hstate_k(const float* __restrict__ hout,
                                                const float* __restrict__ act,
                                                const float* __restrict__ xin,
                                                const float* __restrict__ skip,
                                                float* __restrict__ hs){
  const int i=blockIdx.x*256+threadIdx.x;
  if(i>=(int)N_BSH) return;
  const int bs=i/H_, h=i-bs*H_;
  const float z=xin[(size_t)bs*H2_+H_+h];
  hs[(size_t)bs*H_+h]=(hout[(size_t)bs*H_+h]+skip[h]*act[(size_t)bs*H_+h])*siluf(z);
}

// ============================================================================
extern "C" void kernel_launch(void* const* d_in, const int* in_sizes, int n_in,
                              void* d_out, int out_size, void* d_ws, size_t ws_size,
                              hipStream_t stream){
  float* ws=(float*)d_ws;
  int* flag=(int*)ws;

  float* igb  = ws+O_IGB;
  float* logfb= ws+O_LOGF;
  float* ab   = ws+O_AB;
  float* Mbuf = ws+O_MB;
  float* mtb  = ws+O_MTB;
  float* f_ck = ws+O_CK;
  float* f_cb = ws+O_CB;
  float* f_wq = ws+O_WQ;
  float* f_wk = ws+O_WK;
  float* f_wv = ws+O_WV;
  float* f_wig= ws+O_WIG;
  float* f_big= ws+O_BIG;
  float* f_wfg= ws+O_WFG;
  float* f_bfg= ws+O_BFG;
  float* f_lnw= ws+O_LNW;
  float* f_skp= ws+O_SKP;
  float* f_x  = ws+O_FX;
  float* f_wup= ws+O_FWUP;
  float* f_wdn= ws+O_FWDN;
  float* xin  = ws+O_XIN;
  float* act  = ws+O_ACT;
  float* qb   = ws+O_QB;
  float* kb   = ws+O_KB;
  float* vb   = ws+O_VB;
  float* hraw = ws+O_HRAW;
  float* hout = kb;   // alias: k dead after mlstm_k
  float* hs   = qb;   // alias: q dead after mlstm_k
  float* outf = f_x;  // alias: converted x dead after up-gemm

  detect_k<<<1,256,0,stream>>>((const unsigned short*)d_in[0],flag);
  auto cvt=[&](int idx,float* dst,size_t n){
    convert_k<<<(int)((n+255)/256),256,0,stream>>>(d_in[idx],dst,(int)n,flag);
  };
  cvt(0,f_x,N_X);   cvt(1,f_wup,N_WUP); cvt(2,f_ck,N_CK);  cvt(3,f_cb,H_);
  cvt(4,f_wq,N_WH); cvt(5,f_wk,N_WH);   cvt(6,f_wv,N_WH);  cvt(7,f_wig,N_WG);
  cvt(8,f_big,4);   cvt(9,f_wfg,N_WG);  cvt(10,f_bfg,4);   cvt(11,f_lnw,H_);
  cvt(12,f_skp,H_); cvt(13,f_wdn,N_WDN);

  gemm_s<<<dim3(H2_/16,BS_/16),256,0,stream>>>(f_x,f_wup,xin,BS_,H2_,E_,E_,H2_,H2_);
  conv_act_k<<<(int)((N_BSH+255)/256),256,0,stream>>>(xin,f_ck,f_cb,act);
  qkv_k<<<(int)((N_BSH+255)/256),256,0,stream>>>(act,xin,f_wq,f_wk,f_wv,qb,kb,vb);
  gates_k<<<(BS_*NH_+255)/256,256,0,stream>>>(qb,kb,vb,f_wig,f_big,f_wfg,f_bfg,igb,logfb);
  scan_k<<<1,64,0,stream>>>(igb,logfb,ab,Mbuf,mtb);
  mlstm_k<<<dim3(S_/16,B_*NH_),256,0,stream>>>(qb,kb,vb,ab,Mbuf,mtb,hraw);
  gnorm_k<<<(NG_+255)/256,256,0,stream>>>(hraw,f_lnw,hout);
  hstate_k<<<(int)((N_BSH+255)/256),256,0,stream>>>(hout,act,xin,f_skp,hs);
  gemm_s<<<dim3(E_/16,BS_/16),256,0,stream>>>(hs,f_wdn,outf,BS_,E_,H_,H_,E_,E_);
  out_cast_k<<<(int)((N_X+255)/256),256,0,stream>>>(outf,d_out,flag);
}

// Round 5
// 1958.648 us; speedup vs baseline: 2.2841x; 2.2841x over previous
//
#include <hip/hip_runtime.h>
#include <cmath>

#define DI __device__ __forceinline__

constexpr int B_=2, S_=2048, E_=1024, H_=1344, NH_=4, DH_=336;
constexpr int BS_=B_*S_, H2_=2*H_;
constexpr int NG_=B_*NH_*S_;   // 16384

constexpr size_t N_X=(size_t)BS_*E_;
constexpr size_t N_WUP=(size_t)E_*H2_;
constexpr size_t N_WDN=(size_t)H_*E_;
constexpr size_t N_BSH=(size_t)BS_*H_;
constexpr size_t N_BSH2=(size_t)BS_*H2_;
constexpr size_t N_WH=5376, N_WG=16128, N_CK=4*H_;

// ---- ws layout (floats); identical to round-4 (passed) ----
constexpr size_t O_IGB = 64;
constexpr size_t O_LOGF= O_IGB + NG_;
constexpr size_t O_AB  = O_LOGF+ NG_;
constexpr size_t O_MB  = O_AB  + NG_;
constexpr size_t O_MTB = O_MB  + NG_;
constexpr size_t O_CK  = O_MTB + NG_;
constexpr size_t O_CB  = O_CK  + N_CK;
constexpr size_t O_WQ  = O_CB  + H_;
constexpr size_t O_WK  = O_WQ  + N_WH;
constexpr size_t O_WV  = O_WK  + N_WH;
constexpr size_t O_WIG = O_WV  + N_WH;
constexpr size_t O_BIG = O_WIG + N_WG;
constexpr size_t O_WFG = O_BIG + 16;
constexpr size_t O_BFG = O_WFG + N_WG;
constexpr size_t O_LNW = O_BFG + 16;
constexpr size_t O_SKP = O_LNW + H_;
constexpr size_t O_FX  = O_SKP + H_;
constexpr size_t O_FWUP= O_FX  + N_X;
constexpr size_t O_FWDN= O_FWUP+ N_WUP;
constexpr size_t O_XIN = O_FWDN+ N_WDN;
constexpr size_t O_ACT = O_XIN + N_BSH2;
constexpr size_t O_QB  = O_ACT + N_BSH;
constexpr size_t O_KB  = O_QB  + N_BSH;
constexpr size_t O_VB  = O_KB  + N_BSH;
constexpr size_t O_HOUT= O_VB  + N_BSH;

DI float bf2f(unsigned int u){union{unsigned int i;float f;}v;v.i=(u&0xffffu)<<16;return v.f;}
DI unsigned short f2bf(float f){union{float f;unsigned int i;}v;v.f=f;unsigned int x=v.i;
  return (unsigned short)((x+0x7fffu+((x>>16)&1u))>>16);}
DI float siluf(float x){return x/(1.f+expf(-x));}
DI float logsigf(float x){return (x>=0.f)?-log1pf(expf(-x)):x-log1pf(expf(x));}
DI void load4(const float* p, float* d){float4 v=*reinterpret_cast<const float4*>(p);
  d[0]=v.x;d[1]=v.y;d[2]=v.z;d[3]=v.w;}

// ---- dtype detect (inputs proven fp32 in round 4, keep the guard) ----
__global__ __launch_bounds__(256) void detect_k(const unsigned short* __restrict__ xraw,
                                                int* __restrict__ flag){
  __shared__ int cnt_s;
  if(threadIdx.x==0) cnt_s=0;
  __syncthreads();
  int c=0;
  for(int i=threadIdx.x;i<2048;i+=256){
    const unsigned e=(xraw[i]>>7)&0xFFu;
    if(e>=0x90u) c++;
  }
  atomicAdd(&cnt_s,c);
  __syncthreads();
  if(threadIdx.x==0) *flag=(cnt_s>16)?0:1;
}

__global__ __launch_bounds__(256) void convert_k(const void* __restrict__ src,
                                                 float* __restrict__ dst,int n,
                                                 const int* __restrict__ flag){
  const int i=blockIdx.x*256+threadIdx.x;
  if(i>=n) return;
  if(*flag) dst[i]=bf2f(((const unsigned short*)src)[i]);
  else      dst[i]=((const float*)src)[i];
}

__global__ __launch_bounds__(256) void out_cast_k(const float* __restrict__ src,void* dst,
                                                  const int* __restrict__ flag){
  const int i=blockIdx.x*256+threadIdx.x;
  if(i>=(int)N_X) return;
  const float v=src[i];
  if(*flag) ((unsigned short*)dst)[i]=f2bf(v);
  else      ((float*)dst)[i]=v;
}

// ============================================================================
// 64x64x16 tiled fp32 GEMM, 4x4 register blocking. A:MxK, B:KxN, C:MxN (rm).
// M%64==0, N%64==0, K%16==0.
// ============================================================================
__global__ __launch_bounds__(256) void gemm_k(const float* __restrict__ A,
                                              const float* __restrict__ B,
                                              float* __restrict__ C,
                                              int M,int N,int Kd,int lda,int ldb,int ldc){
  __shared__ float As[16][68];  // As[k][m]
  __shared__ float Bs[16][68];  // Bs[k][n]
  const int t=threadIdx.x;
  const int bn=blockIdx.x*64, bm=blockIdx.y*64;
  const int tx=t&15, ty=t>>4;
  const int a_row=t>>2, a_k4=(t&3)*4;
  const int b_kk=t>>4, b_n4=(t&15)*4;
  float acc[4][4]={};
  for(int k0=0;k0<Kd;k0+=16){
    float av[4], bv[4];
    load4(&A[(size_t)(bm+a_row)*lda+k0+a_k4], av);
    load4(&B[(size_t)(k0+b_kk)*ldb+bn+b_n4], bv);
    __syncthreads();   // prior iteration's LDS reads complete
#pragma unroll
    for(int i=0;i<4;i++) As[a_k4+i][a_row]=av[i];
    *reinterpret_cast<float4*>(&Bs[b_kk][b_n4])=make_float4(bv[0],bv[1],bv[2],bv[3]);
    __syncthreads();
#pragma unroll
    for(int kk=0;kk<16;kk++){
      float a4[4], b4[4];
      load4(&As[kk][ty*4], a4);
      load4(&Bs[kk][tx*4], b4);
#pragma unroll
      for(int i=0;i<4;i++)
#pragma unroll
        for(int j=0;j<4;j++) acc[i][j]+=a4[i]*b4[j];
    }
  }
#pragma unroll
  for(int i=0;i<4;i++)
#pragma unroll
    for(int j=0;j<4;j++)
      C[(size_t)(bm+ty*4+i)*ldc+bn+tx*4+j]=acc[i][j];
}

// ---- causal depthwise conv(K=4)+bias -> SiLU, one thread per (b,s,h) ----
__global__ __launch_bounds__(256) void conv_act_k(const float* __restrict__ xin,
                                                  const float* __restrict__ ck,
                                                  const float* __restrict__ cb,
                                                  float* __restrict__ act){
  const int i=blockIdx.x*256+threadIdx.x;
  if(i>=(int)N_BSH) return;
  const int bs=i/H_, h=i-bs*H_;
  const int b=bs/S_, s=bs-b*S_;
  float xc=cb[h];
#pragma unroll
  for(int w=0;w<4;w++){
    const int sr=s-3+w;
    if(sr>=0) xc+=xin[(size_t)(b*S_+sr)*H2_+h]*ck[w*H_+h];
  }
  act[(size_t)bs*H_+h]=siluf(xc);
}

// ---- headwise q/k/v (PD=4 block-diagonal), one thread per (b,s,h) ----
__global__ __launch_bounds__(256) void qkv_k(const float* __restrict__ act,
                                             const float* __restrict__ xin,
                                             const float* __restrict__ Wq,
                                             const float* __restrict__ Wk,
                                             const float* __restrict__ Wv,
                                             float* __restrict__ qb,float* __restrict__ kb,
                                             float* __restrict__ vb){
  const int i=blockIdx.x*256+threadIdx.x;
  if(i>=(int)N_BSH) return;
  const int bs=i/H_, h=i-bs*H_;
  const int b=bs/S_, s=bs-b*S_;
  const int ph=h>>2, o=h&3, base=ph*4;
  float q=0.f,k=0.f,v=0.f;
#pragma unroll
  for(int d=0;d<4;d++){
    const float a=act[(size_t)bs*H_+base+d];
    const float x=xin[(size_t)bs*H2_+base+d];
    q+=a*Wq[ph*16+d*4+o];
    k+=a*Wk[ph*16+d*4+o];
    v+=x*Wv[ph*16+d*4+o];
  }
  const int nh=h/DH_, dh=h-nh*DH_;
  const size_t off=((size_t)(b*NH_+nh)*S_+s)*DH_+dh;
  qb[off]=q; kb[off]=k; vb[off]=v;
}

// ---- gate pre-activations, one thread per (b,s,n); serial 3H dot ----
__global__ __launch_bounds__(256) void gates_k(const float* __restrict__ qb,
                                               const float* __restrict__ kb,
                                               const float* __restrict__ vb,
                                               const float* __restrict__ Wig,
                                               const float* __restrict__ big,
                                               const float* __restrict__ Wfg,
                                               const float* __restrict__ bfg,
                                               float* __restrict__ igb,float* __restrict__ logfb){
  const int i=blockIdx.x*256+threadIdx.x;
  if(i>=BS_*NH_) return;
  const int bs=i>>2, n=i&3;
  const int b=bs/S_, s=bs-b*S_;
  float sig=0.f,sfg=0.f;
  for(int nh=0;nh<NH_;nh++){
    const size_t rb=((size_t)(b*NH_+nh)*S_+s)*DH_;
    for(int dh=0;dh<DH_;dh++){
      const int h=nh*DH_+dh;
      const float q=qb[rb+dh], k=kb[rb+dh], v=vb[rb+dh];
      sig+=q*Wig[h*4+n]+k*Wig[(H_+h)*4+n]+v*Wig[(2*H_+h)*4+n];
      sfg+=q*Wfg[h*4+n]+k*Wfg[(H_+h)*4+n]+v*Wfg[(2*H_+h)*4+n];
    }
  }
  const size_t off=(size_t)(b*NH_+n)*S_+s;
  igb[off]=sig+big[n];
  logfb[off]=logsigf(sfg+bfg[n]);
}

// ---- fully serial per-head scan (cheap: ~10 µs) ----
__global__ __launch_bounds__(64) void scan_k(const float* __restrict__ igb,
                                             const float* __restrict__ logfb,
                                             float* __restrict__ ab,float* __restrict__ Mb,
                                             float* __restrict__ mtb){
  const int head=threadIdx.x;
  if(head>=B_*NH_) return;
  float c=0.f, M=-1e30f;
  const size_t base=(size_t)head*S_;
  for(int s=0;s<S_;s++){
    c+=logfb[base+s];
    const float a=igb[base+s]-c;
    M=fmaxf(M,a);
    ab[base+s]=a; Mb[base+s]=M; mtb[base+s]=c+M;
  }
}

// ============================================================================
// mLSTM v2: flash-style, block = (head, 32 s-rows), t-tiles of 64.
// QK: d-chunks of 16 staged transposed (Qc[d][s], Kc[d][t]); 2x4 blocking.
// Sc[s][t] = msk * qk*scale*exp(min(a[t]-M[s],0)); PV: 16-row V chunks,
// thread (rg,cg) owns rows rg*4+{0..3} x cols {cg*4, 128+cg*4, 256+cg*4}+0..3.
// Fused: n-normalizer + per-head groupnorm -> hout (B,S,H).
// ============================================================================
__global__ __launch_bounds__(256) void mlstm_k(
    const float* __restrict__ qb, const float* __restrict__ kb, const float* __restrict__ vb,
    const float* __restrict__ ab, const float* __restrict__ Mb, const float* __restrict__ mtb,
    const float* __restrict__ lnw, float* __restrict__ hout){
  const int head=blockIdx.y;
  const int b=head>>2, nh=head&3;
  const int s0=(gridDim.x-1-blockIdx.x)*32;   // heavy blocks dispatch first
  const int t=threadIdx.x;
  const int tx=t&15, ty=t>>4;   // QK: rows ty*2+{0,1}, cols tx*4+{0..3}
  const int rg=t>>5, cg=t&31;   // PV: rows rg*4+{0..3}

  __shared__ float Qc[16][36];
  __shared__ float Kc[16][68];
  __shared__ float Sc[32][68];
  __shared__ float Vs[16][392];
  __shared__ float a_l[64];
  __shared__ float M_l[32];
  __shared__ float red1[32][33];
  __shared__ float red2[32][33];
  __shared__ float mu_s[32], rs_s[32];

  const float* Q =qb+(size_t)head*S_*DH_;
  const float* Kp=kb+(size_t)head*S_*DH_;
  const float* Vp=vb+(size_t)head*S_*DH_;

  float hacc[4][12]={};
  float nsum[4]={};

  if(t<32) M_l[t]=Mb[(size_t)head*S_+s0+t];
  __syncthreads();

  const int ntt=((s0+31)>>6)+1;
  const float scale=0.05455447256f;  // 336^-0.5
  const int lkk=t&15, lr=t>>4;

  for(int ti=0;ti<ntt;ti++){
    const int t0=ti<<6;
    __syncthreads();               // prior tile's Sc/Vs/a_l consumers done
    if(t<64) a_l[t]=ab[(size_t)head*S_+t0+t];

    float qk[2][4]={};
    for(int kc=0;kc<DH_;kc+=16){
      __syncthreads();
      Qc[lkk][lr]      =Q[(size_t)(s0+lr)*DH_+kc+lkk];
      Qc[lkk][lr+16]   =Q[(size_t)(s0+lr+16)*DH_+kc+lkk];
#pragma unroll
      for(int p=0;p<4;p++)
        Kc[lkk][lr+p*16]=Kp[(size_t)(t0+lr+p*16)*DH_+kc+lkk];
      __syncthreads();
#pragma unroll
      for(int kk=0;kk<16;kk++){
        const float2 qv=*reinterpret_cast<const float2*>(&Qc[kk][ty*2]);
        float k4[4];
        load4(&Kc[kk][tx*4], k4);
#pragma unroll
        for(int j=0;j<4;j++){ qk[0][j]+=qv.x*k4[j]; qk[1][j]+=qv.y*k4[j]; }
      }
    }
#pragma unroll
    for(int i=0;i<2;i++){
      const int r=ty*2+i, sg=s0+r;
      float sv[4];
#pragma unroll
      for(int j=0;j<4;j++){
        const int c=tx*4+j, tg=t0+c;
        const float e=fminf(a_l[c]-M_l[r],0.f);     // finite, <=0 on valid pairs
        const float msk=(tg<=sg)?1.f:0.f;
        sv[j]=msk*(qk[i][j]*scale*expf(e));
      }
      *reinterpret_cast<float4*>(&Sc[r][tx*4])=make_float4(sv[0],sv[1],sv[2],sv[3]);
    }
    __syncthreads();
    const int nvc=min(4, ((s0+31-t0)>>4)+1);   // V chunks with start <= s0+31
    for(int vc=0;vc<nvc;vc++){
      if(vc) __syncthreads();
#pragma unroll
      for(int it=0;it<6;it++){
        const int idx=t+it*256;
        const int row=idx/96, c4=idx-row*96;
        float4 val=make_float4(0.f,0.f,0.f,0.f);
        if(c4<84) val=*reinterpret_cast<const float4*>(&Vp[(size_t)(t0+vc*16+row)*DH_+c4*4]);
        *reinterpret_cast<float4*>(&Vs[row][c4*4])=val;
      }
      __syncthreads();
#pragma unroll
      for(int k2=0;k2<16;k2++){
        const int ttg=vc*16+k2;
        float sc[4];
#pragma unroll
        for(int i=0;i<4;i++){ sc[i]=Sc[rg*4+i][ttg]; nsum[i]+=sc[i]; }
#pragma unroll
        for(int j3=0;j3<3;j3++){
          const float4 vv=*reinterpret_cast<const float4*>(&Vs[k2][j3*128+cg*4]);
#pragma unroll
          for(int i=0;i<4;i++){
            hacc[i][j3*4+0]+=sc[i]*vv.x;
            hacc[i][j3*4+1]+=sc[i]*vv.y;
            hacc[i][j3*4+2]+=sc[i]*vv.z;
            hacc[i][j3*4+3]+=sc[i]*vv.w;
          }
        }
      }
    }
  }
  // ---- epilogue: n, normalize, groupnorm, write (B,S,H) ----
  float inv[4];
#pragma unroll
  for(int i=0;i<4;i++){
    const float mt=mtb[(size_t)head*S_+s0+rg*4+i];
    const float n=fmaxf(fabsf(nsum[i]), expf(fminf(fmaxf(-mt,-60.f),60.f)));
    inv[i]=1.f/(n+1e-6f);
  }
  float ls[4]={}, lq[4]={};
#pragma unroll
  for(int i=0;i<4;i++)
#pragma unroll
    for(int j=0;j<12;j++){
      const float h=hacc[i][j]*inv[i];
      hacc[i][j]=h;
      ls[i]+=h;          // pad cols are exact 0
      lq[i]+=h*h;
    }
  __syncthreads();
#pragma unroll
  for(int i=0;i<4;i++){ red1[rg*4+i][cg]=ls[i]; red2[rg*4+i][cg]=lq[i]; }
  __syncthreads();
  if(t<32){
    float s1=0.f,s2=0.f;
#pragma unroll
    for(int c=0;c<32;c++){ s1+=red1[t][c]; s2+=red2[t][c]; }
    const float mu=s1/336.f;
    const float var=s2/336.f-mu*mu;
    mu_s[t]=mu;
    rs_s[t]=rsqrtf(fmaxf(var,0.f)+1e-5f);
  }
  __syncthreads();
  const float* lw=lnw+nh*DH_;
#pragma unroll
  for(int i=0;i<4;i++){
    const int r=rg*4+i;
    const float mu=mu_s[r], rs=rs_s[r];
    float* orow=hout+((size_t)(b*S_+s0+r))*H_+nh*DH_;
#pragma unroll
    for(int j3=0;j3<3;j3++){
      const int col=j3*128+cg*4;
      if(col<DH_){
        const float o0=(hacc[i][j3*4+0]-mu)*rs*lw[col+0];
        const float o1=(hacc[i][j3*4+1]-mu)*rs*lw[col+1];
        const float o2=(hacc[i][j3*4+2]-mu)*rs*lw[col+2];
        const float o3=(hacc[i][j3*4+3]-mu)*rs*lw[col+3];
        *reinterpret_cast<float4*>(&orow[col])=make_float4(o0,o1,o2,o3);
      }
    }
  }
}

// ---- h_state = (h_out + skip*act) * silu(z) ----
__global__ __launch_bounds__(256) void hstate_k(const float* __restrict__ hout,
                                                const float* __restrict__ act,
                                                const float* __restrict__ xin,
                                                const float* __restrict__ skip,
                                                float* __restrict__ hs){
  const int i=blockIdx.x*256+threadIdx.x;
  if(i>=(int)N_BSH) return;
  const int bs=i/H_, h=i-bs*H_;
  const float z=xin[(size_t)bs*H2_+H_+h];
  hs[(size_t)bs*H_+h]=(hout[(size_t)bs*H_+h]+skip[h]*act[(size_t)bs*H_+h])*siluf(z);
}

// ============================================================================
extern "C" void kernel_launch(void* const* d_in, const int* in_sizes, int n_in,
                              void* d_out, int out_size, void* d_ws, size_t ws_size,
                              hipStream_t stream){
  float* ws=(float*)d_ws;
  int* flag=(int*)ws;

  float* igb  = ws+O_IGB;
  float* logfb= ws+O_LOGF;
  float* ab   = ws+O_AB;
  float* Mbuf = ws+O_MB;
  float* mtb  = ws+O_MTB;
  float* f_ck = ws+O_CK;
  float* f_cb = ws+O_CB;
  float* f_wq = ws+O_WQ;
  float* f_wk = ws+O_WK;
  float* f_wv = ws+O_WV;
  float* f_wig= ws+O_WIG;
  float* f_big= ws+O_BIG;
  float* f_wfg= ws+O_WFG;
  float* f_bfg= ws+O_BFG;
  float* f_lnw= ws+O_LNW;
  float* f_skp= ws+O_SKP;
  float* f_x  = ws+O_FX;
  float* f_wup= ws+O_FWUP;
  float* f_wdn= ws+O_FWDN;
  float* xin  = ws+O_XIN;
  float* act  = ws+O_ACT;
  float* qb   = ws+O_QB;
  float* kb   = ws+O_KB;
  float* vb   = ws+O_VB;
  float* hout = ws+O_HOUT;
  float* hs   = qb;   // alias: q dead after mlstm_k
  float* outf = f_x;  // alias: converted x dead after up-gemm

  detect_k<<<1,256,0,stream>>>((const unsigned short*)d_in[0],flag);
  auto cvt=[&](int idx,float* dst,size_t n){
    convert_k<<<(int)((n+255)/256),256,0,stream>>>(d_in[idx],dst,(int)n,flag);
  };
  cvt(0,f_x,N_X);   cvt(1,f_wup,N_WUP); cvt(2,f_ck,N_CK);  cvt(3,f_cb,H_);
  cvt(4,f_wq,N_WH); cvt(5,f_wk,N_WH);   cvt(6,f_wv,N_WH);  cvt(7,f_wig,N_WG);
  cvt(8,f_big,4);   cvt(9,f_wfg,N_WG);  cvt(10,f_bfg,4);   cvt(11,f_lnw,H_);
  cvt(12,f_skp,H_); cvt(13,f_wdn,N_WDN);

  gemm_k<<<dim3(H2_/64,BS_/64),256,0,stream>>>(f_x,f_wup,xin,BS_,H2_,E_,E_,H2_,H2_);
  conv_act_k<<<(int)((N_BSH+255)/256),256,0,stream>>>(xin,f_ck,f_cb,act);
  qkv_k<<<(int)((N_BSH+255)/256),256,0,stream>>>(act,xin,f_wq,f_wk,f_wv,qb,kb,vb);
  gates_k<<<(BS_*NH_+255)/256,256,0,stream>>>(qb,kb,vb,f_wig,f_big,f_wfg,f_bfg,igb,logfb);
  scan_k<<<1,64,0,stream>>>(igb,logfb,ab,Mbuf,mtb);
  mlstm_k<<<dim3(S_/32,B_*NH_),256,0,stream>>>(qb,kb,vb,ab,Mbuf,mtb,f_lnw,hout);
  hstate_k<<<(int)((N_BSH+255)/256),256,0,stream>>>(hout,act,xin,f_skp,hs);
  gemm_k<<<dim3(E_/64,BS_/64),256,0,stream>>>(hs,f_wdn,outf,BS_,E_,H_,H_,E_,E_);
  out_cast_k<<<(int)((N_X+255)/256),256,0,stream>>>(outf,d_out,flag);
}

// Round 6
// 1642.394 us; speedup vs baseline: 2.7239x; 1.1926x over previous
//
#include <hip/hip_runtime.h>
#include <cmath>

#define DI __device__ __forceinline__

constexpr int B_=2, S_=2048, E_=1024, H_=1344, NH_=4, DH_=336;
constexpr int BS_=B_*S_, H2_=2*H_;
constexpr int NG_=B_*NH_*S_;   // 16384
constexpr int DHP_=352;        // DH padded to 11*32 (col 336 = ones for rowsum)

constexpr size_t N_X=(size_t)BS_*E_;
constexpr size_t N_WUP=(size_t)E_*H2_;
constexpr size_t N_WDN=(size_t)H_*E_;
constexpr size_t N_BSH=(size_t)BS_*H_;
constexpr size_t N_BSH2=(size_t)BS_*H2_;
constexpr size_t N_WH=5376, N_WG=16128, N_CK=4*H_;

// ---- ws layout (floats); identical to round-5 (passed) ----
constexpr size_t O_IGB = 64;
constexpr size_t O_LOGF= O_IGB + NG_;
constexpr size_t O_AB  = O_LOGF+ NG_;
constexpr size_t O_MB  = O_AB  + NG_;
constexpr size_t O_MTB = O_MB  + NG_;
constexpr size_t O_CK  = O_MTB + NG_;
constexpr size_t O_CB  = O_CK  + N_CK;
constexpr size_t O_WQ  = O_CB  + H_;
constexpr size_t O_WK  = O_WQ  + N_WH;
constexpr size_t O_WV  = O_WK  + N_WH;
constexpr size_t O_WIG = O_WV  + N_WH;
constexpr size_t O_BIG = O_WIG + N_WG;
constexpr size_t O_WFG = O_BIG + 16;
constexpr size_t O_BFG = O_WFG + N_WG;
constexpr size_t O_LNW = O_BFG + 16;
constexpr size_t O_SKP = O_LNW + H_;
constexpr size_t O_FX  = O_SKP + H_;
constexpr size_t O_FWUP= O_FX  + N_X;
constexpr size_t O_FWDN= O_FWUP+ N_WUP;
constexpr size_t O_XIN = O_FWDN+ N_WDN;
constexpr size_t O_ACT = O_XIN + N_BSH2;
constexpr size_t O_QB  = O_ACT + N_BSH;
constexpr size_t O_KB  = O_QB  + N_BSH;
constexpr size_t O_VB  = O_KB  + N_BSH;
constexpr size_t O_HOUT= O_VB  + N_BSH;

typedef __attribute__((ext_vector_type(8))) short bf16x8;
typedef __attribute__((ext_vector_type(4))) float f32x4;

DI float bf2f(unsigned int u){union{unsigned int i;float f;}v;v.i=(u&0xffffu)<<16;return v.f;}
DI unsigned short f2bf(float f){union{float f;unsigned int i;}v;v.f=f;unsigned int x=v.i;
  return (unsigned short)((x+0x7fffu+((x>>16)&1u))>>16);}
DI float siluf(float x){return x/(1.f+expf(-x));}
DI float logsigf(float x){return (x>=0.f)?-log1pf(expf(-x)):x-log1pf(expf(x));}
DI void load4(const float* p, float* d){float4 v=*reinterpret_cast<const float4*>(p);
  d[0]=v.x;d[1]=v.y;d[2]=v.z;d[3]=v.w;}

// ---- dtype detect (inputs proven fp32 in round 4, keep the guard) ----
__global__ __launch_bounds__(256) void detect_k(const unsigned short* __restrict__ xraw,
                                                int* __restrict__ flag){
  __shared__ int cnt_s;
  if(threadIdx.x==0) cnt_s=0;
  __syncthreads();
  int c=0;
  for(int i=threadIdx.x;i<2048;i+=256){
    const unsigned e=(xraw[i]>>7)&0xFFu;
    if(e>=0x90u) c++;
  }
  atomicAdd(&cnt_s,c);
  __syncthreads();
  if(threadIdx.x==0) *flag=(cnt_s>16)?0:1;
}

__global__ __launch_bounds__(256) void convert_k(const void* __restrict__ src,
                                                 float* __restrict__ dst,int n,
                                                 const int* __restrict__ flag){
  const int i=blockIdx.x*256+threadIdx.x;
  if(i>=n) return;
  if(*flag) dst[i]=bf2f(((const unsigned short*)src)[i]);
  else      dst[i]=((const float*)src)[i];
}

__global__ __launch_bounds__(256) void out_cast_k(const float* __restrict__ src,void* dst,
                                                  const int* __restrict__ flag){
  const int i=blockIdx.x*256+threadIdx.x;
  if(i>=(int)N_X) return;
  const float v=src[i];
  if(*flag) ((unsigned short*)dst)[i]=f2bf(v);
  else      ((float*)dst)[i]=v;
}

// ============================================================================
// 64x64x16 tiled fp32 GEMM, 4x4 register blocking (round-5, passing).
// ============================================================================
__global__ __launch_bounds__(256) void gemm_k(const float* __restrict__ A,
                                              const float* __restrict__ B,
                                              float* __restrict__ C,
                                              int M,int N,int Kd,int lda,int ldb,int ldc){
  __shared__ float As[16][68];
  __shared__ float Bs[16][68];
  const int t=threadIdx.x;
  const int bn=blockIdx.x*64, bm=blockIdx.y*64;
  const int tx=t&15, ty=t>>4;
  const int a_row=t>>2, a_k4=(t&3)*4;
  const int b_kk=t>>4, b_n4=(t&15)*4;
  float acc[4][4]={};
  for(int k0=0;k0<Kd;k0+=16){
    float av[4], bv[4];
    load4(&A[(size_t)(bm+a_row)*lda+k0+a_k4], av);
    load4(&B[(size_t)(k0+b_kk)*ldb+bn+b_n4], bv);
    __syncthreads();
#pragma unroll
    for(int i=0;i<4;i++) As[a_k4+i][a_row]=av[i];
    *reinterpret_cast<float4*>(&Bs[b_kk][b_n4])=make_float4(bv[0],bv[1],bv[2],bv[3]);
    __syncthreads();
#pragma unroll
    for(int kk=0;kk<16;kk++){
      float a4[4], b4[4];
      load4(&As[kk][ty*4], a4);
      load4(&Bs[kk][tx*4], b4);
#pragma unroll
      for(int i=0;i<4;i++)
#pragma unroll
        for(int j=0;j<4;j++) acc[i][j]+=a4[i]*b4[j];
    }
  }
#pragma unroll
  for(int i=0;i<4;i++)
#pragma unroll
    for(int j=0;j<4;j++)
      C[(size_t)(bm+ty*4+i)*ldc+bn+tx*4+j]=acc[i][j];
}

// ---- causal depthwise conv(K=4)+bias -> SiLU ----
__global__ __launch_bounds__(256) void conv_act_k(const float* __restrict__ xin,
                                                  const float* __restrict__ ck,
                                                  const float* __restrict__ cb,
                                                  float* __restrict__ act){
  const int i=blockIdx.x*256+threadIdx.x;
  if(i>=(int)N_BSH) return;
  const int bs=i/H_, h=i-bs*H_;
  const int b=bs/S_, s=bs-b*S_;
  float xc=cb[h];
#pragma unroll
  for(int w=0;w<4;w++){
    const int sr=s-3+w;
    if(sr>=0) xc+=xin[(size_t)(b*S_+sr)*H2_+h]*ck[w*H_+h];
  }
  act[(size_t)bs*H_+h]=siluf(xc);
}

// ---- headwise q/k/v ----
__global__ __launch_bounds__(256) void qkv_k(const float* __restrict__ act,
                                             const float* __restrict__ xin,
                                             const float* __restrict__ Wq,
                                             const float* __restrict__ Wk,
                                             const float* __restrict__ Wv,
                                             float* __restrict__ qb,float* __restrict__ kb,
                                             float* __restrict__ vb){
  const int i=blockIdx.x*256+threadIdx.x;
  if(i>=(int)N_BSH) return;
  const int bs=i/H_, h=i-bs*H_;
  const int b=bs/S_, s=bs-b*S_;
  const int ph=h>>2, o=h&3, base=ph*4;
  float q=0.f,k=0.f,v=0.f;
#pragma unroll
  for(int d=0;d<4;d++){
    const float a=act[(size_t)bs*H_+base+d];
    const float x=xin[(size_t)bs*H2_+base+d];
    q+=a*Wq[ph*16+d*4+o];
    k+=a*Wk[ph*16+d*4+o];
    v+=x*Wv[ph*16+d*4+o];
  }
  const int nh=h/DH_, dh=h-nh*DH_;
  const size_t off=((size_t)(b*NH_+nh)*S_+s)*DH_+dh;
  qb[off]=q; kb[off]=k; vb[off]=v;
}

// ---- V transpose prep: vT[head][d(352)][s] bf16; row 336 = 1.0 (rowsum col),
//      rows 337..351 = 0. LDS-tiled, coalesced both sides. ----
__global__ __launch_bounds__(256) void vprep_k(const float* __restrict__ vb,
                                               unsigned short* __restrict__ vT){
  const int s0=blockIdx.x*64, d0=blockIdx.y*32, head=blockIdx.z;
  const int t=threadIdx.x;
  __shared__ float tile[32][65];
  for(int it=0;it<2;it++){
    const int slot=t+it*256;
    const int r=slot>>3, c0=(slot&7)*4;
#pragma unroll
    for(int jj=0;jj<4;jj++){
      const int d=d0+c0+jj;
      float v;
      if(d<336)       v=vb[((size_t)head*S_+s0+r)*336+d];
      else if(d==336) v=1.f;
      else            v=0.f;
      tile[c0+jj][r]=v;
    }
  }
  __syncthreads();
  const int c=t>>3, r0=(t&7)*8;
  unsigned short h8[8];
#pragma unroll
  for(int j=0;j<8;j++) h8[j]=f2bf(tile[c][r0+j]);
  uint4 pk;
  pk.x=(unsigned)h8[0]|((unsigned)h8[1]<<16);
  pk.y=(unsigned)h8[2]|((unsigned)h8[3]<<16);
  pk.z=(unsigned)h8[4]|((unsigned)h8[5]<<16);
  pk.w=(unsigned)h8[6]|((unsigned)h8[7]<<16);
  *reinterpret_cast<uint4*>(&vT[((size_t)head*DHP_+d0+c)*S_+s0+r0])=pk;
}

// ---- gate pre-activations (round-4, passing) ----
__global__ __launch_bounds__(256) void gates_k(const float* __restrict__ qb,
                                               const float* __restrict__ kb,
                                               const float* __restrict__ vb,
                                               const float* __restrict__ Wig,
                                               const float* __restrict__ big,
                                               const float* __restrict__ Wfg,
                                               const float* __restrict__ bfg,
                                               float* __restrict__ igb,float* __restrict__ logfb){
  const int i=blockIdx.x*256+threadIdx.x;
  if(i>=BS_*NH_) return;
  const int bs=i>>2, n=i&3;
  const int b=bs/S_, s=bs-b*S_;
  float sig=0.f,sfg=0.f;
  for(int nh=0;nh<NH_;nh++){
    const size_t rb=((size_t)(b*NH_+nh)*S_+s)*DH_;
    for(int dh=0;dh<DH_;dh++){
      const int h=nh*DH_+dh;
      const float q=qb[rb+dh], k=kb[rb+dh], v=vb[rb+dh];
      sig+=q*Wig[h*4+n]+k*Wig[(H_+h)*4+n]+v*Wig[(2*H_+h)*4+n];
      sfg+=q*Wfg[h*4+n]+k*Wfg[(H_+h)*4+n]+v*Wfg[(2*H_+h)*4+n];
    }
  }
  const size_t off=(size_t)(b*NH_+n)*S_+s;
  igb[off]=sig+big[n];
  logfb[off]=logsigf(sfg+bfg[n]);
}

// ---- fully serial per-head scan ----
__global__ __launch_bounds__(64) void scan_k(const float* __restrict__ igb,
                                             const float* __restrict__ logfb,
                                             float* __restrict__ ab,float* __restrict__ Mb,
                                             float* __restrict__ mtb){
  const int head=threadIdx.x;
  if(head>=B_*NH_) return;
  float c=0.f, M=-1e30f;
  const size_t base=(size_t)head*S_;
  for(int s=0;s<S_;s++){
    c+=logfb[base+s];
    const float a=igb[base+s]-c;
    M=fmaxf(M,a);
    ab[base+s]=a; Mb[base+s]=M; mtb[base+s]=c+M;
  }
}

// ============================================================================
// mLSTM v3 — MFMA. Block = (head, 32 s-rows); t-chunks of 32.
// Per t-chunk: stage K(32t x 352d) as split hi/lo bf16 in LDS -> QK via
// mfma_f32_16x16x32_bf16 (3 split products, Q frags persistent in regs) ->
// mask/exp epilogue -> Sc bf16 to LDS -> stage V^T (352n x 32t, bf16, from
// pre-transposed vT; n=336 is ones => O[:,336] = rowsum(Sc)) -> PV (11 MFMAs
// per wave). Epilogue: n-normalizer + per-head groupnorm fused.
// Fragment maps (guide §3, m89/m120): A[m=lane&15][k=quad*8+j],
// B[k=quad*8+j][n=lane&15], C/D col=lane&15,row=quad*4+reg.
// ============================================================================
__global__ __launch_bounds__(256) void mlstm_k(
    const float* __restrict__ qb, const float* __restrict__ kb,
    const unsigned short* __restrict__ vT,
    const float* __restrict__ ab, const float* __restrict__ Mb, const float* __restrict__ mtb,
    const float* __restrict__ lnw, float* __restrict__ hout){
  const int head=blockIdx.y;
  const int bI=head>>2, nh=head&3;
  const int s0=(gridDim.x-1-blockIdx.x)*32;   // heavy blocks first
  const int t=threadIdx.x;
  const int w=t>>6, l=t&63;
  const int st=w>>1, tt=w&1;          // s-tile (2x16), t-tile / n-half
  const int lm=l&15, quad=l>>4;

  __shared__ float u_lds[11392];      // union: K hi/lo (45056B) | Vs (22528B) | Otmp fp32 32x356
  __shared__ short Schi[32*32];
  __shared__ float a_l[32], M_l[32], inv_s[32];
  __shared__ float red1[32][9], red2[32][9];
  short* Khi=(short*)u_lds;           // [32][352]
  short* Klo=Khi+32*DHP_;
  short* Vs =Khi;                     // [352][32]
  float* Otmp=u_lds;                  // [32][356]

  // ---- persistent Q fragments (split bf16), 11 d-chunks ----
  bf16x8 qh[11], ql[11];
  {
    const float* qrow=qb+((size_t)head*S_+s0+st*16+lm)*DH_;
#pragma unroll
    for(int dc=0;dc<11;dc++){
      float v[8];
      const int dbase=dc*32+quad*8;
      if(dbase+7<DH_){ load4(qrow+dbase,v); load4(qrow+dbase+4,v+4); }
      else { for(int j=0;j<8;j++) v[j]=0.f; }
#pragma unroll
      for(int j=0;j<8;j++){
        const unsigned short h=f2bf(v[j]);
        qh[dc][j]=(short)h;
        ql[dc][j]=(short)f2bf(v[j]-bf2f(h));
      }
    }
  }
  if(t<32) M_l[t]=Mb[(size_t)head*S_+s0+t];

  f32x4 accO[11];
#pragma unroll
  for(int n=0;n<11;n++) accO[n]={0.f,0.f,0.f,0.f};

  const float scale=0.05455447256f;   // 336^-0.5
  const int nch=(s0>>5)+1;

  for(int tc=0;tc<nch;tc++){
    const int t0=tc<<5;
    __syncthreads();                  // prior PV reads (Vs/Sc) done; M_l ready
    // ---- stage K hi/lo (32 x 352) from fp32 kb ----
    for(int it=0;it<11;it++){
      const int slot=t+it*256;
      const int row=slot/88, g=slot-row*88;
      float v[4];
      if(g<84) load4(&kb[((size_t)head*S_+t0+row)*DH_+g*4], v);
      else { v[0]=v[1]=v[2]=v[3]=0.f; }
      unsigned short h[4], lo[4];
#pragma unroll
      for(int j=0;j<4;j++){ h[j]=f2bf(v[j]); lo[j]=f2bf(v[j]-bf2f(h[j])); }
      *reinterpret_cast<uint2*>(&Khi[row*DHP_+g*4])=
          make_uint2((unsigned)h[0]|((unsigned)h[1]<<16),(unsigned)h[2]|((unsigned)h[3]<<16));
      *reinterpret_cast<uint2*>(&Klo[row*DHP_+g*4])=
          make_uint2((unsigned)lo[0]|((unsigned)lo[1]<<16),(unsigned)lo[2]|((unsigned)lo[3]<<16));
    }
    if(t<32) a_l[t]=ab[(size_t)head*S_+t0+t];
    __syncthreads();                  // K + a_l ready
    // ---- QK: 3 split chains over 11 d-chunks ----
    f32x4 aq0={0,0,0,0}, aq1={0,0,0,0}, aq2={0,0,0,0};
#pragma unroll
    for(int dc=0;dc<11;dc++){
      const bf16x8 kh=*reinterpret_cast<const bf16x8*>(&Khi[(tt*16+lm)*DHP_+dc*32+quad*8]);
      const bf16x8 klv=*reinterpret_cast<const bf16x8*>(&Klo[(tt*16+lm)*DHP_+dc*32+quad*8]);
      aq0=__builtin_amdgcn_mfma_f32_16x16x32_bf16(qh[dc],kh,aq0,0,0,0);
      aq1=__builtin_amdgcn_mfma_f32_16x16x32_bf16(ql[dc],kh,aq1,0,0,0);
      aq2=__builtin_amdgcn_mfma_f32_16x16x32_bf16(qh[dc],klv,aq2,0,0,0);
    }
    __syncthreads();                  // all K-frag reads done -> V may overwrite
    // ---- mask/exp -> Sc bf16 to LDS ----
    {
      const int tg=t0+tt*16+lm;
      const float al=a_l[tt*16+lm];
#pragma unroll
      for(int r=0;r<4;r++){
        const int srow=st*16+quad*4+r;
        const int sg=s0+srow;
        const float qk=aq0[r]+aq1[r]+aq2[r];
        const float e=fminf(al-M_l[srow],0.f);
        const float msk=(tg<=sg)?1.f:0.f;
        Schi[srow*32+tt*16+lm]=(short)f2bf(msk*(qk*scale*expf(e)));
      }
    }
    // ---- stage V^T (352 x 32) bf16 ----
    for(int it=0;it<6;it++){
      const int slot=t+it*256;
      if(slot<1408){
        const int row=slot>>2, g=slot&3;
        *reinterpret_cast<uint4*>(&Vs[row*32+g*8])=
            *reinterpret_cast<const uint4*>(&vT[((size_t)head*DHP_+row)*S_+t0+g*8]);
      }
    }
    __syncthreads();                  // Sc + V ready
    // ---- PV: 11 n-tiles per wave (n-half = tt) ----
    const bf16x8 scf=*reinterpret_cast<const bf16x8*>(&Schi[(st*16+lm)*32+quad*8]);
#pragma unroll
    for(int nt=0;nt<11;nt++){
      const bf16x8 vf=*reinterpret_cast<const bf16x8*>(&Vs[(tt*176+nt*16+lm)*32+quad*8]);
      accO[nt]=__builtin_amdgcn_mfma_f32_16x16x32_bf16(scf,vf,accO[nt],0,0,0);
    }
  }
  // ---- epilogue ----
  __syncthreads();                    // PV done -> KV region reusable as Otmp
  if(tt==1 && lm==0){                 // n-tile 10, col 0 = global n 336 = rowsum
#pragma unroll
    for(int r=0;r<4;r++){
      const int srow=st*16+quad*4+r;
      const float mt=mtb[(size_t)head*S_+s0+srow];
      const float nn=fmaxf(fabsf(accO[10][r]), expf(fminf(fmaxf(-mt,-60.f),60.f)));
      inv_s[srow]=1.f/(nn+1e-6f);
    }
  }
  __syncthreads();
#pragma unroll
  for(int nt=0;nt<11;nt++){
#pragma unroll
    for(int r=0;r<4;r++){
      const int srow=st*16+quad*4+r;
      Otmp[srow*356+tt*176+nt*16+lm]=accO[nt][r]*inv_s[srow];
    }
  }
  __syncthreads();
  // groupnorm: 8 threads per row, 42 cols each (8*42=336)
  {
    const int row=t>>3, sub=t&7;
    float s1=0.f,s2=0.f;
    for(int j=sub*42;j<sub*42+42;j++){ const float h=Otmp[row*356+j]; s1+=h; s2+=h*h; }
    red1[row][sub]=s1; red2[row][sub]=s2;
  }
  __syncthreads();
  {
    const int row=t>>3, sub=t&7;
    if(sub==0){
      float s1=0.f,s2=0.f;
      for(int j=0;j<8;j++){ s1+=red1[row][j]; s2+=red2[row][j]; }
      const float mu=s1/336.f;
      const float var=s2/336.f-mu*mu;
      red1[row][8]=mu;
      red2[row][8]=rsqrtf(fmaxf(var,0.f)+1e-5f);
    }
  }
  __syncthreads();
  {
    const int row=t>>3, sub=t&7;
    const float mu=red1[row][8], rs=red2[row][8];
    float* orow=hout+((size_t)(bI*S_+s0+row))*H_+nh*DH_;
    for(int j=sub*42;j<sub*42+42;j++)
      orow[j]=(Otmp[row*356+j]-mu)*rs*lnw[nh*DH_+j];
  }
}

// ---- h_state = (h_out + skip*act) * silu(z) ----
__global__ __launch_bounds__(256) void hstate_k(const float* __restrict__ hout,
                                                const float* __restrict__ act,
                                                const float* __restrict__ xin,
                                                const float* __restrict__ skip,
                                                float* __restrict__ hs){
  const int i=blockIdx.x*256+threadIdx.x;
  if(i>=(int)N_BSH) return;
  const int bs=i/H_, h=i-bs*H_;
  const float z=xin[(size_t)bs*H2_+H_+h];
  hs[(size_t)bs*H_+h]=(hout[(size_t)bs*H_+h]+skip[h]*act[(size_t)bs*H_+h])*siluf(z);
}

// ============================================================================
extern "C" void kernel_launch(void* const* d_in, const int* in_sizes, int n_in,
                              void* d_out, int out_size, void* d_ws, size_t ws_size,
                              hipStream_t stream){
  float* ws=(float*)d_ws;
  int* flag=(int*)ws;

  float* igb  = ws+O_IGB;
  float* logfb= ws+O_LOGF;
  float* ab   = ws+O_AB;
  float* Mbuf = ws+O_MB;
  float* mtb  = ws+O_MTB;
  float* f_ck = ws+O_CK;
  float* f_cb = ws+O_CB;
  float* f_wq = ws+O_WQ;
  float* f_wk = ws+O_WK;
  float* f_wv = ws+O_WV;
  float* f_wig= ws+O_WIG;
  float* f_big= ws+O_BIG;
  float* f_wfg= ws+O_WFG;
  float* f_bfg= ws+O_BFG;
  float* f_lnw= ws+O_LNW;
  float* f_skp= ws+O_SKP;
  float* f_x  = ws+O_FX;
  float* f_wup= ws+O_FWUP;
  float* f_wdn= ws+O_FWDN;
  float* xin  = ws+O_XIN;
  float* act  = ws+O_ACT;
  float* qb   = ws+O_QB;
  float* kb   = ws+O_KB;
  float* vb   = ws+O_VB;
  float* hout = ws+O_HOUT;
  float* hs   = qb;                            // alias: q dead after mlstm_k
  float* outf = f_x;                           // alias: x dead after up-gemm
  unsigned short* vT=(unsigned short*)f_x;     // alias: x dead after up-gemm; vT dead before outf

  detect_k<<<1,256,0,stream>>>((const unsigned short*)d_in[0],flag);
  auto cvt=[&](int idx,float* dst,size_t n){
    convert_k<<<(int)((n+255)/256),256,0,stream>>>(d_in[idx],dst,(int)n,flag);
  };
  cvt(0,f_x,N_X);   cvt(1,f_wup,N_WUP); cvt(2,f_ck,N_CK);  cvt(3,f_cb,H_);
  cvt(4,f_wq,N_WH); cvt(5,f_wk,N_WH);   cvt(6,f_wv,N_WH);  cvt(7,f_wig,N_WG);
  cvt(8,f_big,4);   cvt(9,f_wfg,N_WG);  cvt(10,f_bfg,4);   cvt(11,f_lnw,H_);
  cvt(12,f_skp,H_); cvt(13,f_wdn,N_WDN);

  gemm_k<<<dim3(H2_/64,BS_/64),256,0,stream>>>(f_x,f_wup,xin,BS_,H2_,E_,E_,H2_,H2_);
  conv_act_k<<<(int)((N_BSH+255)/256),256,0,stream>>>(xin,f_ck,f_cb,act);
  qkv_k<<<(int)((N_BSH+255)/256),256,0,stream>>>(act,xin,f_wq,f_wk,f_wv,qb,kb,vb);
  vprep_k<<<dim3(S_/64,DHP_/32,B_*NH_),256,0,stream>>>(vb,vT);
  gates_k<<<(BS_*NH_+255)/256,256,0,stream>>>(qb,kb,vb,f_wig,f_big,f_wfg,f_bfg,igb,logfb);
  scan_k<<<1,64,0,stream>>>(igb,logfb,ab,Mbuf,mtb);
  mlstm_k<<<dim3(S_/32,B_*NH_),256,0,stream>>>(qb,kb,vT,ab,Mbuf,mtb,f_lnw,hout);
  hstate_k<<<(int)((N_BSH+255)/256),256,0,stream>>>(hout,act,xin,f_skp,hs);
  gemm_k<<<dim3(E_/64,BS_/64),256,0,stream>>>(hs,f_wdn,outf,BS_,E_,H_,H_,E_,E_);
  out_cast_k<<<(int)((N_X+255)/256),256,0,stream>>>(outf,d_out,flag);
}